// Round 1
// baseline (149.897 us; speedup 1.0000x reference)
//
#include <hip/hip_runtime.h>

#define N_NODES 100000
#define N_EDGES 300000

// ---------------------------------------------------------------------------
// Layer 1 edge kernel: one thread per (edge, out_channel).
// msg[e][o] = sum_i x[src][i] * (a0*w[i*32+o][0] + a1*w[i*32+o][1] + b[i*32+o])
// ---------------------------------------------------------------------------
__global__ __launch_bounds__(256) void edge1_kernel(
    const float* __restrict__ x, const int* __restrict__ src,
    const int* __restrict__ dst, const float* __restrict__ ea,
    const float* __restrict__ nn1_w, const float* __restrict__ nn1_b,
    float* __restrict__ agg)
{
    int gid = blockIdx.x * 256 + threadIdx.x;
    int e = gid >> 5;
    int o = gid & 31;
    if (e >= N_EDGES) return;
    int s = src[e], d = dst[e];
    float a0 = ea[2 * e], a1 = ea[2 * e + 1];
    float x0 = x[2 * s], x1 = x[2 * s + 1];
    float w00 = nn1_w[2 * o],        w01 = nn1_w[2 * o + 1];
    float w10 = nn1_w[2 * (32 + o)], w11 = nn1_w[2 * (32 + o) + 1];
    float b0 = nn1_b[o], b1 = nn1_b[32 + o];
    float msg = x0 * fmaf(a0, w00, fmaf(a1, w01, b0))
              + x1 * fmaf(a0, w10, fmaf(a1, w11, b1));
    atomicAdd(&agg[d * 32 + o], msg);
}

// ---------------------------------------------------------------------------
// Node kernel 1: h1 = relu(agg + x@root1 + bias1); then precompute
// P = h1@A, Q = h1@B, R = h1@C where A[i][o]=nn2_w[(i*32+o)*2+0],
// B[i][o]=nn2_w[(i*32+o)*2+1], C[i][o]=nn2_b[i*32+o].
// Block = 256 threads = 8 nodes x 32 channels.
// ---------------------------------------------------------------------------
__global__ __launch_bounds__(256) void node1_kernel(
    const float* __restrict__ x, const float* __restrict__ agg,
    const float* __restrict__ root1, const float* __restrict__ bias1,
    const float* __restrict__ nn2_w, const float* __restrict__ nn2_b,
    float* __restrict__ h1, float* __restrict__ P,
    float* __restrict__ Q, float* __restrict__ R)
{
    __shared__ float As[32 * 32];
    __shared__ float Bs[32 * 32];
    __shared__ float Cs[32 * 32];
    __shared__ float h1s[8][33];
    int t = threadIdx.x;
    for (int k = t; k < 1024; k += 256) {
        As[k] = nn2_w[2 * k];
        Bs[k] = nn2_w[2 * k + 1];
        Cs[k] = nn2_b[k];
    }
    int ln = t >> 5, o = t & 31;
    int n = blockIdx.x * 8 + ln;
    float x0 = x[2 * n], x1 = x[2 * n + 1];
    float h = agg[n * 32 + o] + fmaf(x0, root1[o], fmaf(x1, root1[32 + o], bias1[o]));
    h = fmaxf(h, 0.f);
    h1[n * 32 + o] = h;
    h1s[ln][o] = h;
    __syncthreads();
    float p = 0.f, q = 0.f, r = 0.f;
    #pragma unroll
    for (int i = 0; i < 32; ++i) {
        float hi = h1s[ln][i];
        p = fmaf(hi, As[i * 32 + o], p);
        q = fmaf(hi, Bs[i * 32 + o], q);
        r = fmaf(hi, Cs[i * 32 + o], r);
    }
    P[n * 32 + o] = p;
    Q[n * 32 + o] = q;
    R[n * 32 + o] = r;
}

// ---------------------------------------------------------------------------
// Layer 2 edge kernel: msg[e][o] = a0*P[src][o] + a1*Q[src][o] + R[src][o]
// ---------------------------------------------------------------------------
__global__ __launch_bounds__(256) void edge2_kernel(
    const int* __restrict__ src, const int* __restrict__ dst,
    const float* __restrict__ ea,
    const float* __restrict__ P, const float* __restrict__ Q,
    const float* __restrict__ R, float* __restrict__ agg)
{
    int gid = blockIdx.x * 256 + threadIdx.x;
    int e = gid >> 5;
    int o = gid & 31;
    if (e >= N_EDGES) return;
    int s = src[e], d = dst[e];
    float a0 = ea[2 * e], a1 = ea[2 * e + 1];
    float msg = fmaf(a0, P[s * 32 + o], fmaf(a1, Q[s * 32 + o], R[s * 32 + o]));
    atomicAdd(&agg[d * 32 + o], msg);
}

// ---------------------------------------------------------------------------
// Node kernel 2 (fused epilogue):
// h2 = relu(agg + h1@root2 + bias2); z = relu(h2@fc1_w.T + fc1_b);
// out = z@fc2_w.T + fc2_b.  Block = 8 nodes x 32 lanes.
// ---------------------------------------------------------------------------
__global__ __launch_bounds__(256) void node2_kernel(
    const float* __restrict__ agg, const float* __restrict__ h1,
    const float* __restrict__ root2, const float* __restrict__ bias2,
    const float* __restrict__ fc1_w, const float* __restrict__ fc1_b,
    const float* __restrict__ fc2_w, const float* __restrict__ fc2_b,
    float* __restrict__ out)
{
    __shared__ float r2s[32 * 32];
    __shared__ float f1s[32][33];   // padded: lane j reads row j (stride 33)
    __shared__ float h1s[8][33];
    __shared__ float h2s[8][33];
    int t = threadIdx.x;
    for (int k = t; k < 1024; k += 256) {
        r2s[k] = root2[k];
        f1s[k >> 5][k & 31] = fc1_w[k];
    }
    int ln = t >> 5, o = t & 31;
    int n = blockIdx.x * 8 + ln;
    h1s[ln][o] = h1[n * 32 + o];
    __syncthreads();

    float h = agg[n * 32 + o] + bias2[o];
    #pragma unroll
    for (int i = 0; i < 32; ++i)
        h = fmaf(h1s[ln][i], r2s[i * 32 + o], h);
    h = fmaxf(h, 0.f);
    h2s[ln][o] = h;
    __syncthreads();

    // lane index o acts as fc1 output index j
    float z = fc1_b[o];
    #pragma unroll
    for (int i = 0; i < 32; ++i)
        z = fmaf(h2s[ln][i], f1s[o][i], z);
    z = fmaxf(z, 0.f);

    float tsum = z * fc2_w[o];
    #pragma unroll
    for (int off = 16; off; off >>= 1)
        tsum += __shfl_down(tsum, off, 32);
    if (o == 0) out[n] = tsum + fc2_b[0];
}

extern "C" void kernel_launch(void* const* d_in, const int* in_sizes, int n_in,
                              void* d_out, int out_size, void* d_ws, size_t ws_size,
                              hipStream_t stream) {
    const float* x      = (const float*)d_in[0];
    const int*   ei     = (const int*)d_in[1];
    const float* ea     = (const float*)d_in[2];
    const float* nn1_w  = (const float*)d_in[3];
    const float* nn1_b  = (const float*)d_in[4];
    const float* root1  = (const float*)d_in[5];
    const float* bias1  = (const float*)d_in[6];
    const float* nn2_w  = (const float*)d_in[7];
    const float* nn2_b  = (const float*)d_in[8];
    const float* root2  = (const float*)d_in[9];
    const float* bias2  = (const float*)d_in[10];
    const float* fc1_w  = (const float*)d_in[11];
    const float* fc1_b  = (const float*)d_in[12];
    const float* fc2_w  = (const float*)d_in[13];
    const float* fc2_b  = (const float*)d_in[14];
    float* out = (float*)d_out;

    float* ws  = (float*)d_ws;
    float* agg = ws;                       // N*32
    float* h1  = ws + (size_t)N_NODES * 32;  // N*32
    float* P   = ws + (size_t)N_NODES * 64;  // N*32
    float* Q   = ws + (size_t)N_NODES * 96;  // N*32
    float* R   = ws + (size_t)N_NODES * 128; // N*32

    const int* src = ei;
    const int* dst = ei + N_EDGES;

    hipMemsetAsync(agg, 0, (size_t)N_NODES * 32 * sizeof(float), stream);
    edge1_kernel<<<(N_EDGES * 32) / 256, 256, 0, stream>>>(
        x, src, dst, ea, nn1_w, nn1_b, agg);
    node1_kernel<<<N_NODES / 8, 256, 0, stream>>>(
        x, agg, root1, bias1, nn2_w, nn2_b, h1, P, Q, R);
    hipMemsetAsync(agg, 0, (size_t)N_NODES * 32 * sizeof(float), stream);
    edge2_kernel<<<(N_EDGES * 32) / 256, 256, 0, stream>>>(
        src, dst, ea, P, Q, R, agg);
    node2_kernel<<<N_NODES / 8, 256, 0, stream>>>(
        agg, h1, root2, bias2, fc1_w, fc1_b, fc2_w, fc2_b, out);
}

// Round 2
// 143.431 us; speedup vs baseline: 1.0451x; 1.0451x over previous
//
#include <hip/hip_runtime.h>

#define N_NODES 100000
#define N_EDGES 300000

// ---------------------------------------------------------------------------
// Zero both aggregation buffers in one launch (replaces 2x hipMemsetAsync,
// which dispatched a ~272 GB/s fill kernel costing 47 us each).
// ---------------------------------------------------------------------------
__global__ __launch_bounds__(256) void zero_ws_kernel(float4* __restrict__ p,
                                                      int n4)
{
    int stride = gridDim.x * 256;
    for (int i = blockIdx.x * 256 + threadIdx.x; i < n4; i += stride)
        p[i] = make_float4(0.f, 0.f, 0.f, 0.f);
}

// ---------------------------------------------------------------------------
// Layer 1 edge kernel: one thread per (edge, out_channel).
// msg[e][o] = sum_i x[src][i] * (a0*w[i*32+o][0] + a1*w[i*32+o][1] + b[i*32+o])
// ---------------------------------------------------------------------------
__global__ __launch_bounds__(256) void edge1_kernel(
    const float* __restrict__ x, const int* __restrict__ src,
    const int* __restrict__ dst, const float* __restrict__ ea,
    const float* __restrict__ nn1_w, const float* __restrict__ nn1_b,
    float* __restrict__ agg)
{
    int gid = blockIdx.x * 256 + threadIdx.x;
    int e = gid >> 5;
    int o = gid & 31;
    if (e >= N_EDGES) return;
    int s = src[e], d = dst[e];
    float a0 = ea[2 * e], a1 = ea[2 * e + 1];
    float x0 = x[2 * s], x1 = x[2 * s + 1];
    float w00 = nn1_w[2 * o],        w01 = nn1_w[2 * o + 1];
    float w10 = nn1_w[2 * (32 + o)], w11 = nn1_w[2 * (32 + o) + 1];
    float b0 = nn1_b[o], b1 = nn1_b[32 + o];
    float msg = x0 * fmaf(a0, w00, fmaf(a1, w01, b0))
              + x1 * fmaf(a0, w10, fmaf(a1, w11, b1));
    atomicAdd(&agg[d * 32 + o], msg);
}

// ---------------------------------------------------------------------------
// Node kernel 1: h1 = relu(agg + x@root1 + bias1); then precompute
// P = h1@A, Q = h1@B, R = h1@C where A[i][o]=nn2_w[(i*32+o)*2+0],
// B[i][o]=nn2_w[(i*32+o)*2+1], C[i][o]=nn2_b[i*32+o].
// Block = 256 threads = 8 nodes x 32 channels.
// ---------------------------------------------------------------------------
__global__ __launch_bounds__(256) void node1_kernel(
    const float* __restrict__ x, const float* __restrict__ agg,
    const float* __restrict__ root1, const float* __restrict__ bias1,
    const float* __restrict__ nn2_w, const float* __restrict__ nn2_b,
    float* __restrict__ h1, float* __restrict__ P,
    float* __restrict__ Q, float* __restrict__ R)
{
    __shared__ float As[32 * 32];
    __shared__ float Bs[32 * 32];
    __shared__ float Cs[32 * 32];
    __shared__ float h1s[8][33];
    int t = threadIdx.x;
    for (int k = t; k < 1024; k += 256) {
        As[k] = nn2_w[2 * k];
        Bs[k] = nn2_w[2 * k + 1];
        Cs[k] = nn2_b[k];
    }
    int ln = t >> 5, o = t & 31;
    int n = blockIdx.x * 8 + ln;
    float x0 = x[2 * n], x1 = x[2 * n + 1];
    float h = agg[n * 32 + o] + fmaf(x0, root1[o], fmaf(x1, root1[32 + o], bias1[o]));
    h = fmaxf(h, 0.f);
    h1[n * 32 + o] = h;
    h1s[ln][o] = h;
    __syncthreads();
    float p = 0.f, q = 0.f, r = 0.f;
    #pragma unroll
    for (int i = 0; i < 32; ++i) {
        float hi = h1s[ln][i];
        p = fmaf(hi, As[i * 32 + o], p);
        q = fmaf(hi, Bs[i * 32 + o], q);
        r = fmaf(hi, Cs[i * 32 + o], r);
    }
    P[n * 32 + o] = p;
    Q[n * 32 + o] = q;
    R[n * 32 + o] = r;
}

// ---------------------------------------------------------------------------
// Layer 2 edge kernel: msg[e][o] = a0*P[src][o] + a1*Q[src][o] + R[src][o]
// ---------------------------------------------------------------------------
__global__ __launch_bounds__(256) void edge2_kernel(
    const int* __restrict__ src, const int* __restrict__ dst,
    const float* __restrict__ ea,
    const float* __restrict__ P, const float* __restrict__ Q,
    const float* __restrict__ R, float* __restrict__ agg)
{
    int gid = blockIdx.x * 256 + threadIdx.x;
    int e = gid >> 5;
    int o = gid & 31;
    if (e >= N_EDGES) return;
    int s = src[e], d = dst[e];
    float a0 = ea[2 * e], a1 = ea[2 * e + 1];
    float msg = fmaf(a0, P[s * 32 + o], fmaf(a1, Q[s * 32 + o], R[s * 32 + o]));
    atomicAdd(&agg[d * 32 + o], msg);
}

// ---------------------------------------------------------------------------
// Node kernel 2 (fused epilogue):
// h2 = relu(agg + h1@root2 + bias2); z = relu(h2@fc1_w.T + fc1_b);
// out = z@fc2_w.T + fc2_b.  Block = 8 nodes x 32 lanes.
// ---------------------------------------------------------------------------
__global__ __launch_bounds__(256) void node2_kernel(
    const float* __restrict__ agg, const float* __restrict__ h1,
    const float* __restrict__ root2, const float* __restrict__ bias2,
    const float* __restrict__ fc1_w, const float* __restrict__ fc1_b,
    const float* __restrict__ fc2_w, const float* __restrict__ fc2_b,
    float* __restrict__ out)
{
    __shared__ float r2s[32 * 32];
    __shared__ float f1s[32][33];   // padded: lane j reads row j (stride 33)
    __shared__ float h1s[8][33];
    __shared__ float h2s[8][33];
    int t = threadIdx.x;
    for (int k = t; k < 1024; k += 256) {
        r2s[k] = root2[k];
        f1s[k >> 5][k & 31] = fc1_w[k];
    }
    int ln = t >> 5, o = t & 31;
    int n = blockIdx.x * 8 + ln;
    h1s[ln][o] = h1[n * 32 + o];
    __syncthreads();

    float h = agg[n * 32 + o] + bias2[o];
    #pragma unroll
    for (int i = 0; i < 32; ++i)
        h = fmaf(h1s[ln][i], r2s[i * 32 + o], h);
    h = fmaxf(h, 0.f);
    h2s[ln][o] = h;
    __syncthreads();

    // lane index o acts as fc1 output index j
    float z = fc1_b[o];
    #pragma unroll
    for (int i = 0; i < 32; ++i)
        z = fmaf(h2s[ln][i], f1s[o][i], z);
    z = fmaxf(z, 0.f);

    float tsum = z * fc2_w[o];
    #pragma unroll
    for (int off = 16; off; off >>= 1)
        tsum += __shfl_down(tsum, off, 32);
    if (o == 0) out[n] = tsum + fc2_b[0];
}

extern "C" void kernel_launch(void* const* d_in, const int* in_sizes, int n_in,
                              void* d_out, int out_size, void* d_ws, size_t ws_size,
                              hipStream_t stream) {
    const float* x      = (const float*)d_in[0];
    const int*   ei     = (const int*)d_in[1];
    const float* ea     = (const float*)d_in[2];
    const float* nn1_w  = (const float*)d_in[3];
    const float* nn1_b  = (const float*)d_in[4];
    const float* root1  = (const float*)d_in[5];
    const float* bias1  = (const float*)d_in[6];
    const float* nn2_w  = (const float*)d_in[7];
    const float* nn2_b  = (const float*)d_in[8];
    const float* root2  = (const float*)d_in[9];
    const float* bias2  = (const float*)d_in[10];
    const float* fc1_w  = (const float*)d_in[11];
    const float* fc1_b  = (const float*)d_in[12];
    const float* fc2_w  = (const float*)d_in[13];
    const float* fc2_b  = (const float*)d_in[14];
    float* out = (float*)d_out;

    float* ws   = (float*)d_ws;
    float* agg1 = ws;                         // N*32
    float* agg2 = ws + (size_t)N_NODES * 32;  // N*32
    float* h1   = ws + (size_t)N_NODES * 64;  // N*32
    float* P    = ws + (size_t)N_NODES * 96;  // N*32
    float* Q    = ws + (size_t)N_NODES * 128; // N*32
    float* R    = ws + (size_t)N_NODES * 160; // N*32

    const int* src = ei;
    const int* dst = ei + N_EDGES;

    // Zero agg1+agg2 (contiguous, 2*N*32 floats) in one vectorized launch.
    int n4 = (N_NODES * 64) / 4;
    zero_ws_kernel<<<2048, 256, 0, stream>>>((float4*)agg1, n4);

    edge1_kernel<<<(N_EDGES * 32) / 256, 256, 0, stream>>>(
        x, src, dst, ea, nn1_w, nn1_b, agg1);
    node1_kernel<<<N_NODES / 8, 256, 0, stream>>>(
        x, agg1, root1, bias1, nn2_w, nn2_b, h1, P, Q, R);
    edge2_kernel<<<(N_EDGES * 32) / 256, 256, 0, stream>>>(
        src, dst, ea, P, Q, R, agg2);
    node2_kernel<<<N_NODES / 8, 256, 0, stream>>>(
        agg2, h1, root2, bias2, fc1_w, fc1_b, fc2_w, fc2_b, out);
}